// Round 11
// baseline (669.193 us; speedup 1.0000x reference)
//
#include <hip/hip_runtime.h>
#include <cmath>

// Problem constants
#define S_LEN 2048
#define HID 4096
#define NHEAD 32
#define Q_LORA 1536
#define KV_LORA 512
#define NOPE 128
#define ROPE_D 64
#define VDIM 128
#define QK_DIM 192       // NOPE + ROPE
#define FUSED_N 2112     // Q_LORA + KV_LORA + ROPE
#define FUSED_NPAD 2304  // padded to a multiple of 256 (for 256-wide GEMM tiles)

typedef __attribute__((ext_vector_type(8))) short short8;
typedef __attribute__((ext_vector_type(4))) short short4v;
typedef __attribute__((ext_vector_type(4))) float floatx4;
typedef unsigned short ushort_t;

// float -> bf16 bits, round-to-nearest-even
__device__ inline short f2bf(float f) {
    union { float f; unsigned u; } v; v.f = f;
    unsigned r = (v.u + 0x7fffu + ((v.u >> 16) & 1u)) >> 16;
    return (short)r;
}
__device__ inline float bf2f(ushort_t u) {
    union { unsigned u; float f; } v; v.u = ((unsigned)u) << 16; return v.f;
}

// async 16B global -> LDS (LDS dest: wave-uniform base + lane*16)
#define GLOAD16(g, l)                                                        \
    __builtin_amdgcn_global_load_lds(                                        \
        (const __attribute__((address_space(1))) unsigned int*)(g),          \
        (__attribute__((address_space(3))) unsigned int*)(l), 16, 0, 0)

__device__ inline short8 conv8(const float* s) {
    const float4* s4 = (const float4*)s;
    float4 a = s4[0], b = s4[1];
    short8 v;
    v[0] = f2bf(a.x); v[1] = f2bf(a.y); v[2] = f2bf(a.z); v[3] = f2bf(a.w);
    v[4] = f2bf(b.x); v[5] = f2bf(b.y); v[6] = f2bf(b.z); v[7] = f2bf(b.w);
    return v;
}

// ---------------------------------------------------------------------------
// Merged fp32->bf16 conversion of hs, w_a (padded to 2304 rows), w_qb, w_kvb.
// ---------------------------------------------------------------------------
#define CE0 (S_LEN * HID)                    //  8388608  hs
#define CE1 (CE0 + FUSED_NPAD * HID)         // +9437184  w_a padded
#define CE2 (CE1 + NHEAD * QK_DIM * Q_LORA)  // +9437184  w_qb
#define CE3 (CE2 + NHEAD * 256 * KV_LORA)    // +4194304  w_kvb

__global__ __launch_bounds__(256) void conv_all(
    const float* __restrict__ hs, const float* __restrict__ w_a,
    const float* __restrict__ w_qb, const float* __restrict__ w_kvb,
    ushort_t* __restrict__ hs_bf, ushort_t* __restrict__ w_a_bf,
    ushort_t* __restrict__ w_qb_bf, ushort_t* __restrict__ w_kvb_bf)
{
    int i = (blockIdx.x * 256 + threadIdx.x) * 8;
    if (i < CE0) {
        *(short8*)(hs_bf + i) = conv8(hs + i);
    } else if (i < CE1) {
        int j = i - CE0;
        short8 v;
        if (j < FUSED_N * HID) v = conv8(w_a + j);
        else                   v = (short8){0,0,0,0,0,0,0,0};
        *(short8*)(w_a_bf + j) = v;
    } else if (i < CE2) {
        int j = i - CE1;
        *(short8*)(w_qb_bf + j) = conv8(w_qb + j);
    } else if (i < CE3) {
        int j = i - CE2;
        *(short8*)(w_kvb_bf + j) = conv8(w_kvb + j);
    }
}

// plain converter (used for w_o after gemm1 frees its region)
__global__ __launch_bounds__(256) void conv_bf16(
    const float* __restrict__ src, ushort_t* __restrict__ dst, int n)
{
    int i = (blockIdx.x * 256 + threadIdx.x) * 8;
    if (i >= n) return;
    *(short8*)(dst + i) = conv8(src + i);
}

// ---------------------------------------------------------------------------
// fp32 pairwise add (split-K reduce): o = p0 + p1
// ---------------------------------------------------------------------------
__global__ __launch_bounds__(256) void reduce_add_f32(
    const float* __restrict__ p0, const float* __restrict__ p1,
    float* __restrict__ o, int n)
{
    int i = (blockIdx.x * 256 + threadIdx.x) * 4;
    if (i >= n) return;
    float4 a = *(const float4*)(p0 + i);
    float4 b = *(const float4*)(p1 + i);
    float4 c; c.x = a.x + b.x; c.y = a.y + b.y; c.z = a.z + b.z; c.w = a.w + b.w;
    *(float4*)(o + i) = c;
}

// ---------------------------------------------------------------------------
// 256x256 bf16 MFMA GEMM, counted-vmcnt 4-buffer SINGLE-BARRIER pipeline.
// (Round-8/9 proven. Stage-2-ahead is the max safe pre-barrier depth:
//  stage at iter i writes slot (i+2)&3 = compute(i-2)'s slot, and any wave
//  past barrier_{i-1} implies all waves finished compute(i-2).)
// ---------------------------------------------------------------------------
__device__ __forceinline__ void gemm_pipe_body(
    const ushort_t* __restrict__ A, int lda,
    const ushort_t* __restrict__ B, int ldb,
    int m0, int n0, int kbeg, int nst,
    short8* LDS, floatx4 (&acc)[8][4], int tid)
{
    const int lane = tid & 63;
    const int wave = tid >> 6;
    const int m    = lane & 15;
    const int quad = lane >> 4;
    const int wr   = wave >> 2;           // 0..1
    const int wc   = wave & 3;            // 0..3

    auto stage = [&](int k0, int buf) {
        short8* dst = &LDS[buf * 2048];
        #pragma unroll
        for (int r = 0; r < 2; ++r) {
            int i  = tid + r * 512;       // 0..1023
            int mi = i & 15, qd = (i >> 4) & 3, rb = i >> 6;
            GLOAD16(A + (size_t)(m0 + rb * 16 + mi) * lda + k0 + qd * 8, dst + i);
            GLOAD16(B + (size_t)(n0 + rb * 16 + mi) * ldb + k0 + qd * 8, dst + 1024 + i);
        }
    };

    // prologue: 2 stages in flight (8 loads/thread outstanding)
    stage(kbeg, 0);
    stage(kbeg + 32, 1);

    for (int i = 0; i < nst; ++i) {
        if (i + 2 < nst) {
            stage(kbeg + (i + 2) * 32, (i + 2) & 3);
            // 12 outstanding -> wait oldest 4 (= stage i) done, 8 stay in flight
            asm volatile("s_waitcnt vmcnt(8)" ::: "memory");
        } else if (i + 1 < nst) {
            asm volatile("s_waitcnt vmcnt(4)" ::: "memory");   // stage i done
        } else {
            asm volatile("s_waitcnt vmcnt(0)" ::: "memory");   // last stage done
        }
        asm volatile("s_barrier" ::: "memory");   // buf i ready for ALL waves

        const short8* As = &LDS[(i & 3) * 2048];
        const short8* Bs = As + 1024;
        short8 af[8], bfr[4];
        #pragma unroll
        for (int ii = 0; ii < 8; ++ii)
            af[ii] = As[((wr * 8 + ii) * 4 + quad) * 16 + m];
        #pragma unroll
        for (int j = 0; j < 4; ++j)
            bfr[j] = Bs[((wc * 4 + j) * 4 + quad) * 16 + m];

        __builtin_amdgcn_s_setprio(1);
        #pragma unroll
        for (int ri = 0; ri < 8; ++ri)
            #pragma unroll
            for (int ci = 0; ci < 4; ++ci)
                acc[ri][ci] = __builtin_amdgcn_mfma_f32_16x16x32_bf16(
                    af[ri], bfr[ci], acc[ri][ci], 0, 0, 0);
        __builtin_amdgcn_s_setprio(0);
        // no trailing barrier: slot-reuse distance 4 makes it redundant
    }
}

__device__ inline void store_c(float* p, float v)    { *p = v; }
__device__ inline void store_c(ushort_t* p, float v) { *p = (ushort_t)f2bf(v); }

template <typename CT>
__device__ __forceinline__ void gemm256_store(
    CT* __restrict__ C, int ldc, int N, int m0, int n0,
    floatx4 (&acc)[8][4], int tid)
{
    const int lane = tid & 63;
    const int wave = tid >> 6;
    const int m    = lane & 15;
    const int quad = lane >> 4;
    const int wr   = wave >> 2, wc = wave & 3;
    #pragma unroll
    for (int ci = 0; ci < 4; ++ci) {
        int col = n0 + wc * 64 + ci * 16 + m;
        if (col < N) {
            #pragma unroll
            for (int ri = 0; ri < 8; ++ri) {
                int row = m0 + wr * 128 + ri * 16 + quad * 4;
                #pragma unroll
                for (int r = 0; r < 4; ++r)
                    store_c(&C[(size_t)(row + r) * ldc + col], acc[ri][ci][r]);
            }
        }
    }
}

// generic pipelined 256^2 GEMM, 1-D grid = nx*ny*nz (z = split-K plane),
// bijective XCD swizzle (requires gridDim.x % 8 == 0), x fastest.
template <typename CT>
__global__ __launch_bounds__(512) void gemm256p(
    const ushort_t* __restrict__ A, int lda,
    const ushort_t* __restrict__ B, int ldb,
    CT* __restrict__ C, int ldc, int N, int Klen, int nx, int ny)
{
    __shared__ short8 LDS[4 * 2048];   // 128 KB
    const int tid = threadIdx.x;

    const int nwg = gridDim.x;
    const int bid = blockIdx.x;
    const int wg  = (bid & 7) * (nwg >> 3) + (bid >> 3);
    const int nxy = nx * ny;
    const int z   = wg / nxy;
    const int rxy = wg - z * nxy;
    const int m0  = (rxy / nx) * 256;
    const int n0  = (rxy % nx) * 256;
    CT* Cz = C + (size_t)z * (size_t)ny * 256 * ldc;

    floatx4 acc[8][4];
    #pragma unroll
    for (int i = 0; i < 8; ++i)
        #pragma unroll
        for (int j = 0; j < 4; ++j) acc[i][j] = (floatx4){0.f, 0.f, 0.f, 0.f};

    gemm_pipe_body(A, lda, B, ldb, m0, n0, z * Klen, Klen >> 5, LDS, acc, tid);
    gemm256_store<CT>(Cz, ldc, N, m0, n0, acc, tid);
}

// merged gemm3 (q = cq @ w_qb^T) + gemm4 (kv = ckv @ w_kvb^T), pipelined.
// gemm4 blocks cover exactly one head: k-half -> kv_bf, v-half stored
// DIRECTLY into blocked vt layout (transpose fused).
__global__ __launch_bounds__(512) void gemm34p(
    const ushort_t* __restrict__ a_bf,
    const ushort_t* __restrict__ w_qb_bf,
    const ushort_t* __restrict__ w_kvb_bf,
    ushort_t* __restrict__ q_bf,
    ushort_t* __restrict__ kv_bf,
    ushort_t* __restrict__ vt)
{
    __shared__ short8 LDS[4 * 2048];   // 128 KB
    const int tid = threadIdx.x;

    const int nwg = gridDim.x;         // 448
    const int bid = blockIdx.x;
    const int wg  = (bid & 7) * (nwg >> 3) + (bid >> 3);
    const int x   = wg % 56;
    const int m0  = (wg / 56) * 256;

    const ushort_t* A; const ushort_t* B;
    int ldb, K, n0;
    if (x < 24) {   // gemm3
        A = a_bf;            B = w_qb_bf;
        ldb = Q_LORA;        K = Q_LORA;   n0 = x * 256;
    } else {        // gemm4
        A = a_bf + Q_LORA;   B = w_kvb_bf;
        ldb = KV_LORA;       K = KV_LORA;  n0 = (x - 24) * 256;
    }

    floatx4 acc[8][4];
    #pragma unroll
    for (int i = 0; i < 8; ++i)
        #pragma unroll
        for (int j = 0; j < 4; ++j) acc[i][j] = (floatx4){0.f, 0.f, 0.f, 0.f};

    gemm_pipe_body(A, FUSED_N, B, ldb, m0, n0, 0, K >> 5, LDS, acc, tid);

    const int lane = tid & 63;
    const int wave = tid >> 6;
    const int m    = lane & 15;
    const int quad = lane >> 4;
    const int wr   = wave >> 2, wc = wave & 3;

    if (x < 24) {
        gemm256_store<ushort_t>(q_bf, NHEAD * QK_DIM, NHEAD * QK_DIM, m0, n0, acc, tid);
    } else {
        const int h = x - 24;              // one head per block
        #pragma unroll
        for (int ci = 0; ci < 4; ++ci) {
            int dd = wc * 64 + ci * 16 + m;            // 0..255 within head
            if (dd < 128) {
                #pragma unroll
                for (int ri = 0; ri < 8; ++ri) {
                    int row = m0 + wr * 128 + ri * 16 + quad * 4;
                    #pragma unroll
                    for (int r = 0; r < 4; ++r)
                        kv_bf[(size_t)(row + r) * (NHEAD * 256) + h * 256 + dd] =
                            (ushort_t)f2bf(acc[ri][ci][r]);
                }
            } else {
                int d = dd - 128;
                #pragma unroll
                for (int ri = 0; ri < 8; ++ri) {
                    int row0 = m0 + wr * 128 + ri * 16 + quad * 4;  // row0&7 in {0,4}
                    short4v v4;
                    #pragma unroll
                    for (int r = 0; r < 4; ++r) v4[r] = f2bf(acc[ri][ci][r]);
                    *(short4v*)(vt + (((size_t)h * (S_LEN / 8) + (row0 >> 3)) * 128 + d) * 8
                                   + (row0 & 7)) = v4;
                }
            }
        }
    }
}

// ---------------------------------------------------------------------------
// Fused split-K reduce (4 planes) + RMSNorm(cq), RMSNorm(ckv) + RoPE(k_pe).
// ---------------------------------------------------------------------------
__global__ __launch_bounds__(256) void norm_rope_kernel(
    const float* __restrict__ part,
    ushort_t* __restrict__ a,
    const float* __restrict__ q_ln_w,
    const float* __restrict__ kv_ln_w,
    const int* __restrict__ pos_ids)
{
    const int s = blockIdx.x;
    const size_t PL = (size_t)S_LEN * FUSED_N;
    const float* r0 = part + (size_t)s * FUSED_N;
    ushort_t* row = a + (size_t)s * FUSED_N;
    __shared__ float red[256];
    const int tid = threadIdx.x;

    float vq[6];
    float ss = 0.f;
    #pragma unroll
    for (int j = 0; j < 6; ++j) {
        int i = tid + j * 256;
        vq[j] = (r0[i] + r0[i + PL]) + (r0[i + 2 * PL] + r0[i + 3 * PL]);
        ss += vq[j] * vq[j];
    }
    red[tid] = ss;
    __syncthreads();
    for (int w = 128; w > 0; w >>= 1) {
        if (tid < w) red[tid] += red[tid + w];
        __syncthreads();
    }
    float scale_q = rsqrtf(red[0] / (float)Q_LORA + 1e-6f);
    #pragma unroll
    for (int j = 0; j < 6; ++j) {
        int i = tid + j * 256;
        row[i] = (ushort_t)f2bf(vq[j] * scale_q * q_ln_w[i]);
    }
    __syncthreads();

    float vk[2];
    ss = 0.f;
    #pragma unroll
    for (int j = 0; j < 2; ++j) {
        int iw = tid + j * 256;
        int i  = Q_LORA + iw;
        vk[j] = (r0[i] + r0[i + PL]) + (r0[i + 2 * PL] + r0[i + 3 * PL]);
        ss += vk[j] * vk[j];
    }
    red[tid] = ss;
    __syncthreads();
    for (int w = 128; w > 0; w >>= 1) {
        if (tid < w) red[tid] += red[tid + w];
        __syncthreads();
    }
    float scale_kv = rsqrtf(red[0] / (float)KV_LORA + 1e-6f);
    #pragma unroll
    for (int j = 0; j < 2; ++j) {
        int iw = tid + j * 256;
        row[Q_LORA + iw] = (ushort_t)f2bf(vk[j] * scale_kv * kv_ln_w[iw]);
    }

    if (tid < 32) {
        const int j = tid;
        float pos = (float)pos_ids[s];
        float inv_freq = expf(-(float)j * (9.210340371976184f / 32.f));
        float ang = pos * inv_freq;
        float c = cosf(ang), sn = sinf(ang);
        int i1 = Q_LORA + KV_LORA + j;
        int i2 = i1 + 32;
        float x1 = (r0[i1] + r0[i1 + PL]) + (r0[i1 + 2 * PL] + r0[i1 + 3 * PL]);
        float x2 = (r0[i2] + r0[i2 + PL]) + (r0[i2 + 2 * PL] + r0[i2 + 3 * PL]);
        row[i1] = (ushort_t)f2bf(x1 * c - x2 * sn);
        row[i2] = (ushort_t)f2bf(x2 * c + x1 * sn);
    }
}

// ---------------------------------------------------------------------------
// MFMA bf16 flash attention (causal), counted-vmcnt 3-buffer single-barrier
// pipeline, DUAL q-tile per block with SHARED K/V staging:
//   q-tile B (=pair) key range [0, ntB) is a prefix of q-tile A (=31-pair)
//   range [0, ntA): one k-loop over ntA tiles; both q-tiles computed while
//   tt < ntB. Staged tiles/block: 66 -> 64-2*pair (avg 49, worst 64 < 66).
//   RoPE on q_pe fused into the Q-load (rope pair (j,j+32) = elements e of
//   qf[4]/qf[5] in the SAME lane); rope_q kernel removed (q_bf only consumer).
// ---------------------------------------------------------------------------
#define ATTN_PROCESS(qf, O, mrow, lrow, qrb)                                   \
    {                                                                          \
        floatx4 s0 = (floatx4){0.f, 0.f, 0.f, 0.f};                            \
        floatx4 s1 = (floatx4){0.f, 0.f, 0.f, 0.f};                            \
        const int kb = quad * 32 + m;                                          \
        __builtin_amdgcn_s_setprio(1);                                         \
        _Pragma("unroll")                                                      \
        for (int c = 0; c < 6; ++c) {                                          \
            s0 = __builtin_amdgcn_mfma_f32_16x16x32_bf16(qf[c], KF[cur][c * 128 + kb],      s0, 0, 0, 0); \
            s1 = __builtin_amdgcn_mfma_f32_16x16x32_bf16(qf[c], KF[cur][c * 128 + kb + 16], s1, 0, 0, 0); \
        }                                                                      \
        __builtin_amdgcn_s_setprio(0);                                         \
        const int qb = (qrb) + quad * 4;                                       \
        float sv0[4], sv1[4];                                                  \
        _Pragma("unroll")                                                      \
        for (int r = 0; r < 4; ++r) {                                          \
            float a0 = s0[r] * scale2;                                         \
            float a1 = s1[r] * scale2;                                         \
            if (t0 + m > qb + r)      a0 = -1e30f;                             \
            if (t0 + 16 + m > qb + r) a1 = -1e30f;                             \
            sv0[r] = a0; sv1[r] = a1;                                          \
        }                                                                      \
        _Pragma("unroll")                                                      \
        for (int r = 0; r < 4; ++r) {                                          \
            float v = fmaxf(sv0[r], sv1[r]);                                   \
            if (!__all(v <= mrow[r] + 8.f)) {                                  \
                v = fmaxf(v, __shfl_xor(v, 1));                                \
                v = fmaxf(v, __shfl_xor(v, 2));                                \
                v = fmaxf(v, __shfl_xor(v, 4));                                \
                v = fmaxf(v, __shfl_xor(v, 8));                                \
                float mnew  = fmaxf(mrow[r], v);                               \
                float alpha = exp2f(mrow[r] - mnew);                           \
                lrow[r] *= alpha;                                              \
                _Pragma("unroll")                                              \
                for (int t = 0; t < 8; ++t) O[t][r] *= alpha;                  \
                mrow[r] = mnew;                                                \
            }                                                                  \
            float p0 = exp2f(sv0[r] - mrow[r]);                                \
            float p1 = exp2f(sv1[r] - mrow[r]);                                \
            lrow[r] += p0 + p1;                                                \
            int rw = quad * 4 + r;                                             \
            short* pw = pas + wave * 512;                                      \
            pw[((m >> 3) + 0) * 128 + rw * 8 + (m & 7)] = f2bf(p0);            \
            pw[((m >> 3) + 2) * 128 + rw * 8 + (m & 7)] = f2bf(p1);            \
        }                                                                      \
        short8 pfrag = PA[wave * 64 + quad * 16 + m];                          \
        __builtin_amdgcn_s_setprio(1);                                         \
        _Pragma("unroll")                                                      \
        for (int t = 0; t < 8; ++t) {                                          \
            O[t] = __builtin_amdgcn_mfma_f32_16x16x32_bf16(                    \
                pfrag, VF[cur][quad * 128 + m + 16 * t], O[t], 0, 0, 0);       \
        }                                                                      \
        __builtin_amdgcn_s_setprio(0);                                         \
    }

__global__ __launch_bounds__(256) void attn_mfma(
    const ushort_t* __restrict__ q,
    const ushort_t* __restrict__ kv,
    const ushort_t* __restrict__ abuf,
    const ushort_t* __restrict__ vt,
    const int* __restrict__ pos_ids,
    ushort_t* __restrict__ attn)
{
    __shared__ short8 KF[3][768];   // 36 KB
    __shared__ short8 VF[3][512];   // 24 KB
    __shared__ short8 PA[256];      //  4 KB

    const int tid  = threadIdx.x;
    const int wave = tid >> 6;
    const int lane = tid & 63;
    const int m    = lane & 15;
    const int quad = lane >> 4;
    const int h    = blockIdx.y;
    const int pair = blockIdx.x;                  // 0..15
    const int qtA  = 31 - pair, qtB = pair;
    const int ntA  = 2 * qtA + 2, ntB = 2 * qtB + 2;   // ntB <= ntA

    const float scale2 = 0.07216878364870323f * 1.4426950408889634f;
    short* pas = (short*)PA;

    auto stage_kv = [&](int t0, int buf) {       // exactly 5 GLOAD16 / thread
        #pragma unroll
        for (int rep = 0; rep < 3; ++rep) {
            int i   = rep * 256 + tid;
            int key = i & 31, qd = (i >> 5) & 3, c = i >> 7;   // c wave-uniform
            if (c < 4)
                GLOAD16(kv + ((size_t)(t0 + key) * NHEAD + h) * 256 + c * 32 + qd * 8,
                        &KF[buf][i]);
            else
                GLOAD16(abuf + (size_t)(t0 + key) * FUSED_N + 2048 + (c - 4) * 32 + qd * 8,
                        &KF[buf][i]);
        }
        const ushort_t* vsrc = vt + ((size_t)h * (S_LEN / 8) + (t0 >> 3)) * 1024;
        GLOAD16(vsrc + (size_t)tid * 8, &VF[buf][tid]);
        GLOAD16(vsrc + (size_t)(256 + tid) * 8, &VF[buf][256 + tid]);
    };

    // Q load + fused RoPE (pairs (j, j+32) live in qf[4][e] / qf[5][e])
    short8 qfA[6], qfB[6];
    {
        int rowA = qtA * 64 + wave * 16 + m;
        int rowB = qtB * 64 + wave * 16 + m;
        const ushort_t* qra = q + ((size_t)rowA * NHEAD + h) * QK_DIM;
        const ushort_t* qrb = q + ((size_t)rowB * NHEAD + h) * QK_DIM;
        #pragma unroll
        for (int c = 0; c < 6; ++c) {
            qfA[c] = *(const short8*)(qra + c * 32 + quad * 8);
            qfB[c] = *(const short8*)(qrb + c * 32 + quad * 8);
        }
        float posA = (float)pos_ids[rowA];
        float posB = (float)pos_ids[rowB];
        #pragma unroll
        for (int e = 0; e < 8; ++e) {
            int j = quad * 8 + e;
            float inv_freq = expf(-(float)j * (9.210340371976184f / 32.f));
            float angA = posA * inv_freq, angB = posB * inv_freq;
            float cA = cosf(angA), sA = sinf(angA);
            float cB = cosf(angB), sB = sinf(angB);
            float xa1 = bf2f((ushort_t)qfA[4][e]), xa2 = bf2f((ushort_t)qfA[5][e]);
            float xb1 = bf2f((ushort_t)qfB[4][e]), xb2 = bf2f((ushort_t)qfB[5][e]);
            qfA[4][e] = f2bf(xa1 * cA - xa2 * sA);
            qfA[5][e] = f2bf(xa2 * cA + xa1 * sA);
            qfB[4][e] = f2bf(xb1 * cB - xb2 * sB);
            qfB[5][e] = f2bf(xb2 * cB + xb1 * sB);
        }
    }

    floatx4 OA[8], OB[8];
    #pragma unroll
    for (int t = 0; t < 8; ++t) {
        OA[t] = (floatx4){0.f, 0.f, 0.f, 0.f};
        OB[t] = (floatx4){0.f, 0.f, 0.f, 0.f};
    }
    float mA[4] = {-1e30f, -1e30f, -1e30f, -1e30f};
    float lA[4] = {0.f, 0.f, 0.f, 0.f};
    float mB[4] = {-1e30f, -1e30f, -1e30f, -1e30f};
    float lB[4] = {0.f, 0.f, 0.f, 0.f};

    const int qrbA = qtA * 64 + wave * 16;
    const int qrbB = qtB * 64 + wave * 16;

    stage_kv(0, 0);                          // prologue: 1 tile ahead

    for (int tt = 0; tt < ntA; ++tt) {
        const int t0 = tt * 32;
        if (tt + 1 < ntA) {
            stage_kv(t0 + 32, (tt + 1) % 3);
            asm volatile("s_waitcnt vmcnt(5)" ::: "memory");   // tile tt done
        } else {
            asm volatile("s_waitcnt vmcnt(0)" ::: "memory");
        }
        asm volatile("s_barrier" ::: "memory");   // buf tt ready for ALL waves
        const int cur = tt % 3;

        ATTN_PROCESS(qfA, OA, mA, lA, qrbA);
        if (tt < ntB) ATTN_PROCESS(qfB, OB, mB, lB, qrbB);
        // no trailing barrier (3-slot single-barrier scheme, round-10 proven)
    }

    #pragma unroll
    for (int r = 0; r < 4; ++r) {
        float la = lA[r];
        la += __shfl_xor(la, 1);
        la += __shfl_xor(la, 2);
        la += __shfl_xor(la, 4);
        la += __shfl_xor(la, 8);
        float linvA = 1.f / la;
        int rowA = qrbA + quad * 4 + r;
        ushort_t* dstA = attn + ((size_t)rowA * NHEAD + h) * VDIM + m;
        #pragma unroll
        for (int t = 0; t < 8; ++t)
            dstA[16 * t] = (ushort_t)f2bf(OA[t][r] * linvA);

        float lb = lB[r];
        lb += __shfl_xor(lb, 1);
        lb += __shfl_xor(lb, 2);
        lb += __shfl_xor(lb, 4);
        lb += __shfl_xor(lb, 8);
        float linvB = 1.f / lb;
        int rowB = qrbB + quad * 4 + r;
        ushort_t* dstB = attn + ((size_t)rowB * NHEAD + h) * VDIM + m;
        #pragma unroll
        for (int t = 0; t < 8; ++t)
            dstB[16 * t] = (ushort_t)f2bf(OB[t][r] * linvB);
    }
}

// ---------------------------------------------------------------------------
extern "C" void kernel_launch(void* const* d_in, const int* in_sizes, int n_in,
                              void* d_out, int out_size, void* d_ws, size_t ws_size,
                              hipStream_t stream)
{
    const int*   pos    = (const int*)d_in[0];
    const float* hs     = (const float*)d_in[1];
    const float* w_a    = (const float*)d_in[2];
    const float* qlnw   = (const float*)d_in[3];
    const float* kvlnw  = (const float*)d_in[4];
    const float* w_qb   = (const float*)d_in[5];
    const float* w_kvb  = (const float*)d_in[6];
    const float* w_o    = (const float*)d_in[7];
    float* out = (float*)d_out;

    // workspace layout — 163.8 MB total (>=168 MB known available)
    char* p = (char*)d_ws;
    ushort_t* a_bf    = (ushort_t*)p; p += (size_t)S_LEN * FUSED_N * 2;          //  8.65 MB
    ushort_t* q_bf    = (ushort_t*)p; p += (size_t)S_LEN * NHEAD * QK_DIM * 2;   // 25.2 MB
    ushort_t* kv_bf   = (ushort_t*)p; p += (size_t)S_LEN * NHEAD * 256 * 2;      // 33.6 MB
    ushort_t* attn_bf = (ushort_t*)p; p += (size_t)S_LEN * HID * 2;              // 16.8 MB
    ushort_t* hs_bf   = (ushort_t*)p; p += (size_t)S_LEN * HID * 2;              // 16.8 MB
    ushort_t* w_a_bf  = (ushort_t*)p; p += (size_t)FUSED_NPAD * HID * 2;         // 18.9 MB
    ushort_t* w_qb_bf = (ushort_t*)p; p += (size_t)NHEAD * QK_DIM * Q_LORA * 2;  // 18.9 MB
    ushort_t* w_kvb_bf= (ushort_t*)p; p += (size_t)NHEAD * 256 * KV_LORA * 2;    //  8.4 MB
    ushort_t* vt_bf   = (ushort_t*)p; p += (size_t)S_LEN * HID * 2;              // 16.8 MB
    // w_o_bf (33.6 MB) aliases hs_bf + w_a_bf, both dead after gemm 1
    ushort_t* w_o_bf  = hs_bf;
    // gemm1 split-K=4 fp32 partials (69.2 MB) in q_bf+kv_bf+attn_bf (75.5 MB)
    float* part1 = (float*)q_bf;
    // gemm7 split-K=2 fp32 partials (67.1 MB) in a_bf+q_bf+kv_bf (67.4 MB)
    float* part7 = (float*)a_bf;

    if (ws_size < (size_t)(p - (char*)d_ws)) return;  // fail loud, not fault

    dim3 blk(256);
    dim3 blk512(512);
    auto cgrid = [](size_t n) { return dim3((unsigned)((n / 8 + 255) / 256)); };

    // 0. merged fp32 -> bf16 (hs, w_a pad, w_qb, w_kvb) — one dispatch
    conv_all<<<dim3(CE3 / 2048), blk, 0, stream>>>(
        hs, w_a, w_qb, w_kvb, hs_bf, w_a_bf, w_qb_bf, w_kvb_bf);

    // 1. a = hs @ w_fused_a^T : pipelined 256^2, split-K=4 (288 blocks)
    gemm256p<float><<<dim3((FUSED_NPAD / 256) * (S_LEN / 256) * 4), blk512, 0, stream>>>(
        hs_bf, HID, w_a_bf, HID, part1, FUSED_N, FUSED_N, HID / 4,
        FUSED_NPAD / 256, S_LEN / 256);

    // 1b. w_o -> bf16 (into region freed by gemm 1)
    conv_bf16<<<cgrid((size_t)HID * HID), blk, 0, stream>>>(w_o, w_o_bf, HID * HID);

    // 2. fused split-K reduce (4 planes) + RMSNorm cq/ckv + k_pe RoPE -> a_bf
    norm_rope_kernel<<<S_LEN, 256, 0, stream>>>(part1, a_bf, qlnw, kvlnw, pos);

    // 3+4. merged q/kv projection GEMMs, pipelined, V-transpose fused (448 blocks)
    gemm34p<<<dim3(56 * (S_LEN / 256)), blk512, 0, stream>>>(
        a_bf, w_qb_bf, w_kvb_bf, q_bf, kv_bf, vt_bf);

    // 5+6. MFMA flash attention (q_pe RoPE fused into Q-load; shared-KV dual
    //      q-tile) -> attn (2048, 32, 128) bf16
    attn_mfma<<<dim3(16, NHEAD), blk, 0, stream>>>(
        q_bf, kv_bf, a_bf, vt_bf, pos, attn_bf);

    // 7. out = attn @ w_o^T : pipelined 256^2, split-K=2 (256 blocks), then add
    gemm256p<float><<<dim3((HID / 256) * (S_LEN / 256) * 2), blk512, 0, stream>>>(
        attn_bf, HID, w_o_bf, HID, part7, HID, HID, HID / 2,
        HID / 256, S_LEN / 256);
    reduce_add_f32<<<cgrid((size_t)S_LEN * HID * 2), blk, 0, stream>>>(
        part7, part7 + (size_t)S_LEN * HID, out, S_LEN * HID);
}

// Round 12
// 566.400 us; speedup vs baseline: 1.1815x; 1.1815x over previous
//
#include <hip/hip_runtime.h>
#include <cmath>

// Problem constants
#define S_LEN 2048
#define HID 4096
#define NHEAD 32
#define Q_LORA 1536
#define KV_LORA 512
#define NOPE 128
#define ROPE_D 64
#define VDIM 128
#define QK_DIM 192       // NOPE + ROPE
#define FUSED_N 2112     // Q_LORA + KV_LORA + ROPE
#define FUSED_NPAD 2304  // padded to a multiple of 256 (for 256-wide GEMM tiles)

typedef __attribute__((ext_vector_type(8))) short short8;
typedef __attribute__((ext_vector_type(4))) short short4v;
typedef __attribute__((ext_vector_type(4))) float floatx4;
typedef unsigned short ushort_t;

// float -> bf16 bits, round-to-nearest-even
__device__ inline short f2bf(float f) {
    union { float f; unsigned u; } v; v.f = f;
    unsigned r = (v.u + 0x7fffu + ((v.u >> 16) & 1u)) >> 16;
    return (short)r;
}
__device__ inline float bf2f(ushort_t u) {
    union { unsigned u; float f; } v; v.u = ((unsigned)u) << 16; return v.f;
}

// async 16B global -> LDS (LDS dest: wave-uniform base + lane*16)
#define GLOAD16(g, l)                                                        \
    __builtin_amdgcn_global_load_lds(                                        \
        (const __attribute__((address_space(1))) unsigned int*)(g),          \
        (__attribute__((address_space(3))) unsigned int*)(l), 16, 0, 0)

__device__ inline short8 conv8(const float* s) {
    const float4* s4 = (const float4*)s;
    float4 a = s4[0], b = s4[1];
    short8 v;
    v[0] = f2bf(a.x); v[1] = f2bf(a.y); v[2] = f2bf(a.z); v[3] = f2bf(a.w);
    v[4] = f2bf(b.x); v[5] = f2bf(b.y); v[6] = f2bf(b.z); v[7] = f2bf(b.w);
    return v;
}

// ---------------------------------------------------------------------------
// Merged fp32->bf16 conversion of hs, w_a (padded to 2304 rows), w_qb, w_kvb.
// ---------------------------------------------------------------------------
#define CE0 (S_LEN * HID)                    //  8388608  hs
#define CE1 (CE0 + FUSED_NPAD * HID)         // +9437184  w_a padded
#define CE2 (CE1 + NHEAD * QK_DIM * Q_LORA)  // +9437184  w_qb
#define CE3 (CE2 + NHEAD * 256 * KV_LORA)    // +4194304  w_kvb

__global__ __launch_bounds__(256) void conv_all(
    const float* __restrict__ hs, const float* __restrict__ w_a,
    const float* __restrict__ w_qb, const float* __restrict__ w_kvb,
    ushort_t* __restrict__ hs_bf, ushort_t* __restrict__ w_a_bf,
    ushort_t* __restrict__ w_qb_bf, ushort_t* __restrict__ w_kvb_bf)
{
    int i = (blockIdx.x * 256 + threadIdx.x) * 8;
    if (i < CE0) {
        *(short8*)(hs_bf + i) = conv8(hs + i);
    } else if (i < CE1) {
        int j = i - CE0;
        short8 v;
        if (j < FUSED_N * HID) v = conv8(w_a + j);
        else                   v = (short8){0,0,0,0,0,0,0,0};
        *(short8*)(w_a_bf + j) = v;
    } else if (i < CE2) {
        int j = i - CE1;
        *(short8*)(w_qb_bf + j) = conv8(w_qb + j);
    } else if (i < CE3) {
        int j = i - CE2;
        *(short8*)(w_kvb_bf + j) = conv8(w_kvb + j);
    }
}

// plain converter (used for w_o after gemm1 frees its region)
__global__ __launch_bounds__(256) void conv_bf16(
    const float* __restrict__ src, ushort_t* __restrict__ dst, int n)
{
    int i = (blockIdx.x * 256 + threadIdx.x) * 8;
    if (i >= n) return;
    *(short8*)(dst + i) = conv8(src + i);
}

// ---------------------------------------------------------------------------
// fp32 pairwise add (split-K reduce): o = p0 + p1
// ---------------------------------------------------------------------------
__global__ __launch_bounds__(256) void reduce_add_f32(
    const float* __restrict__ p0, const float* __restrict__ p1,
    float* __restrict__ o, int n)
{
    int i = (blockIdx.x * 256 + threadIdx.x) * 4;
    if (i >= n) return;
    float4 a = *(const float4*)(p0 + i);
    float4 b = *(const float4*)(p1 + i);
    float4 c; c.x = a.x + b.x; c.y = a.y + b.y; c.z = a.z + b.z; c.w = a.w + b.w;
    *(float4*)(o + i) = c;
}

// ---------------------------------------------------------------------------
// 256x256 bf16 MFMA GEMM, counted-vmcnt 4-buffer SINGLE-BARRIER pipeline.
// (Round-8/9/10 proven. Stage-2-ahead is the max safe pre-barrier depth:
//  stage at iter i writes slot (i+2)&3 = compute(i-2)'s slot, and any wave
//  past barrier_{i-1} implies all waves finished compute(i-2).)
// ---------------------------------------------------------------------------
__device__ __forceinline__ void gemm_pipe_body(
    const ushort_t* __restrict__ A, int lda,
    const ushort_t* __restrict__ B, int ldb,
    int m0, int n0, int kbeg, int nst,
    short8* LDS, floatx4 (&acc)[8][4], int tid)
{
    const int lane = tid & 63;
    const int wave = tid >> 6;
    const int m    = lane & 15;
    const int quad = lane >> 4;
    const int wr   = wave >> 2;           // 0..1
    const int wc   = wave & 3;            // 0..3

    auto stage = [&](int k0, int buf) {
        short8* dst = &LDS[buf * 2048];
        #pragma unroll
        for (int r = 0; r < 2; ++r) {
            int i  = tid + r * 512;       // 0..1023
            int mi = i & 15, qd = (i >> 4) & 3, rb = i >> 6;
            GLOAD16(A + (size_t)(m0 + rb * 16 + mi) * lda + k0 + qd * 8, dst + i);
            GLOAD16(B + (size_t)(n0 + rb * 16 + mi) * ldb + k0 + qd * 8, dst + 1024 + i);
        }
    };

    // prologue: 2 stages in flight (8 loads/thread outstanding)
    stage(kbeg, 0);
    stage(kbeg + 32, 1);

    for (int i = 0; i < nst; ++i) {
        if (i + 2 < nst) {
            stage(kbeg + (i + 2) * 32, (i + 2) & 3);
            // 12 outstanding -> wait oldest 4 (= stage i) done, 8 stay in flight
            asm volatile("s_waitcnt vmcnt(8)" ::: "memory");
        } else if (i + 1 < nst) {
            asm volatile("s_waitcnt vmcnt(4)" ::: "memory");   // stage i done
        } else {
            asm volatile("s_waitcnt vmcnt(0)" ::: "memory");   // last stage done
        }
        asm volatile("s_barrier" ::: "memory");   // buf i ready for ALL waves

        const short8* As = &LDS[(i & 3) * 2048];
        const short8* Bs = As + 1024;
        short8 af[8], bfr[4];
        #pragma unroll
        for (int ii = 0; ii < 8; ++ii)
            af[ii] = As[((wr * 8 + ii) * 4 + quad) * 16 + m];
        #pragma unroll
        for (int j = 0; j < 4; ++j)
            bfr[j] = Bs[((wc * 4 + j) * 4 + quad) * 16 + m];

        __builtin_amdgcn_s_setprio(1);
        #pragma unroll
        for (int ri = 0; ri < 8; ++ri)
            #pragma unroll
            for (int ci = 0; ci < 4; ++ci)
                acc[ri][ci] = __builtin_amdgcn_mfma_f32_16x16x32_bf16(
                    af[ri], bfr[ci], acc[ri][ci], 0, 0, 0);
        __builtin_amdgcn_s_setprio(0);
        // no trailing barrier: slot-reuse distance 4 makes it redundant
    }
}

__device__ inline void store_c(float* p, float v)    { *p = v; }
__device__ inline void store_c(ushort_t* p, float v) { *p = (ushort_t)f2bf(v); }

template <typename CT>
__device__ __forceinline__ void gemm256_store(
    CT* __restrict__ C, int ldc, int N, int m0, int n0,
    floatx4 (&acc)[8][4], int tid)
{
    const int lane = tid & 63;
    const int wave = tid >> 6;
    const int m    = lane & 15;
    const int quad = lane >> 4;
    const int wr   = wave >> 2, wc = wave & 3;
    #pragma unroll
    for (int ci = 0; ci < 4; ++ci) {
        int col = n0 + wc * 64 + ci * 16 + m;
        if (col < N) {
            #pragma unroll
            for (int ri = 0; ri < 8; ++ri) {
                int row = m0 + wr * 128 + ri * 16 + quad * 4;
                #pragma unroll
                for (int r = 0; r < 4; ++r)
                    store_c(&C[(size_t)(row + r) * ldc + col], acc[ri][ci][r]);
            }
        }
    }
}

// generic pipelined 256^2 GEMM, 1-D grid = nx*ny*nz (z = split-K plane),
// bijective XCD swizzle (requires gridDim.x % 8 == 0), x fastest.
template <typename CT>
__global__ __launch_bounds__(512) void gemm256p(
    const ushort_t* __restrict__ A, int lda,
    const ushort_t* __restrict__ B, int ldb,
    CT* __restrict__ C, int ldc, int N, int Klen, int nx, int ny)
{
    __shared__ short8 LDS[4 * 2048];   // 128 KB
    const int tid = threadIdx.x;

    const int nwg = gridDim.x;
    const int bid = blockIdx.x;
    const int wg  = (bid & 7) * (nwg >> 3) + (bid >> 3);
    const int nxy = nx * ny;
    const int z   = wg / nxy;
    const int rxy = wg - z * nxy;
    const int m0  = (rxy / nx) * 256;
    const int n0  = (rxy % nx) * 256;
    CT* Cz = C + (size_t)z * (size_t)ny * 256 * ldc;

    floatx4 acc[8][4];
    #pragma unroll
    for (int i = 0; i < 8; ++i)
        #pragma unroll
        for (int j = 0; j < 4; ++j) acc[i][j] = (floatx4){0.f, 0.f, 0.f, 0.f};

    gemm_pipe_body(A, lda, B, ldb, m0, n0, z * Klen, Klen >> 5, LDS, acc, tid);
    gemm256_store<CT>(Cz, ldc, N, m0, n0, acc, tid);
}

// merged gemm3 (q = cq @ w_qb^T) + gemm4 (kv = ckv @ w_kvb^T), pipelined.
// gemm4 blocks cover exactly one head: k-half -> kv_bf, v-half stored
// DIRECTLY into blocked vt layout (transpose fused).
__global__ __launch_bounds__(512) void gemm34p(
    const ushort_t* __restrict__ a_bf,
    const ushort_t* __restrict__ w_qb_bf,
    const ushort_t* __restrict__ w_kvb_bf,
    ushort_t* __restrict__ q_bf,
    ushort_t* __restrict__ kv_bf,
    ushort_t* __restrict__ vt)
{
    __shared__ short8 LDS[4 * 2048];   // 128 KB
    const int tid = threadIdx.x;

    const int nwg = gridDim.x;         // 448
    const int bid = blockIdx.x;
    const int wg  = (bid & 7) * (nwg >> 3) + (bid >> 3);
    const int x   = wg % 56;
    const int m0  = (wg / 56) * 256;

    const ushort_t* A; const ushort_t* B;
    int ldb, K, n0;
    if (x < 24) {   // gemm3
        A = a_bf;            B = w_qb_bf;
        ldb = Q_LORA;        K = Q_LORA;   n0 = x * 256;
    } else {        // gemm4
        A = a_bf + Q_LORA;   B = w_kvb_bf;
        ldb = KV_LORA;       K = KV_LORA;  n0 = (x - 24) * 256;
    }

    floatx4 acc[8][4];
    #pragma unroll
    for (int i = 0; i < 8; ++i)
        #pragma unroll
        for (int j = 0; j < 4; ++j) acc[i][j] = (floatx4){0.f, 0.f, 0.f, 0.f};

    gemm_pipe_body(A, FUSED_N, B, ldb, m0, n0, 0, K >> 5, LDS, acc, tid);

    const int lane = tid & 63;
    const int wave = tid >> 6;
    const int m    = lane & 15;
    const int quad = lane >> 4;
    const int wr   = wave >> 2, wc = wave & 3;

    if (x < 24) {
        gemm256_store<ushort_t>(q_bf, NHEAD * QK_DIM, NHEAD * QK_DIM, m0, n0, acc, tid);
    } else {
        const int h = x - 24;              // one head per block
        #pragma unroll
        for (int ci = 0; ci < 4; ++ci) {
            int dd = wc * 64 + ci * 16 + m;            // 0..255 within head
            if (dd < 128) {
                #pragma unroll
                for (int ri = 0; ri < 8; ++ri) {
                    int row = m0 + wr * 128 + ri * 16 + quad * 4;
                    #pragma unroll
                    for (int r = 0; r < 4; ++r)
                        kv_bf[(size_t)(row + r) * (NHEAD * 256) + h * 256 + dd] =
                            (ushort_t)f2bf(acc[ri][ci][r]);
                }
            } else {
                int d = dd - 128;
                #pragma unroll
                for (int ri = 0; ri < 8; ++ri) {
                    int row0 = m0 + wr * 128 + ri * 16 + quad * 4;  // row0&7 in {0,4}
                    short4v v4;
                    #pragma unroll
                    for (int r = 0; r < 4; ++r) v4[r] = f2bf(acc[ri][ci][r]);
                    *(short4v*)(vt + (((size_t)h * (S_LEN / 8) + (row0 >> 3)) * 128 + d) * 8
                                   + (row0 & 7)) = v4;
                }
            }
        }
    }
}

// ---------------------------------------------------------------------------
// Fused split-K reduce (4 planes) + RMSNorm(cq), RMSNorm(ckv) + RoPE(k_pe).
// ---------------------------------------------------------------------------
__global__ __launch_bounds__(256) void norm_rope_kernel(
    const float* __restrict__ part,
    ushort_t* __restrict__ a,
    const float* __restrict__ q_ln_w,
    const float* __restrict__ kv_ln_w,
    const int* __restrict__ pos_ids)
{
    const int s = blockIdx.x;
    const size_t PL = (size_t)S_LEN * FUSED_N;
    const float* r0 = part + (size_t)s * FUSED_N;
    ushort_t* row = a + (size_t)s * FUSED_N;
    __shared__ float red[256];
    const int tid = threadIdx.x;

    float vq[6];
    float ss = 0.f;
    #pragma unroll
    for (int j = 0; j < 6; ++j) {
        int i = tid + j * 256;
        vq[j] = (r0[i] + r0[i + PL]) + (r0[i + 2 * PL] + r0[i + 3 * PL]);
        ss += vq[j] * vq[j];
    }
    red[tid] = ss;
    __syncthreads();
    for (int w = 128; w > 0; w >>= 1) {
        if (tid < w) red[tid] += red[tid + w];
        __syncthreads();
    }
    float scale_q = rsqrtf(red[0] / (float)Q_LORA + 1e-6f);
    #pragma unroll
    for (int j = 0; j < 6; ++j) {
        int i = tid + j * 256;
        row[i] = (ushort_t)f2bf(vq[j] * scale_q * q_ln_w[i]);
    }
    __syncthreads();

    float vk[2];
    ss = 0.f;
    #pragma unroll
    for (int j = 0; j < 2; ++j) {
        int iw = tid + j * 256;
        int i  = Q_LORA + iw;
        vk[j] = (r0[i] + r0[i + PL]) + (r0[i + 2 * PL] + r0[i + 3 * PL]);
        ss += vk[j] * vk[j];
    }
    red[tid] = ss;
    __syncthreads();
    for (int w = 128; w > 0; w >>= 1) {
        if (tid < w) red[tid] += red[tid + w];
        __syncthreads();
    }
    float scale_kv = rsqrtf(red[0] / (float)KV_LORA + 1e-6f);
    #pragma unroll
    for (int j = 0; j < 2; ++j) {
        int iw = tid + j * 256;
        row[Q_LORA + iw] = (ushort_t)f2bf(vk[j] * scale_kv * kv_ln_w[iw]);
    }

    if (tid < 32) {
        const int j = tid;
        float pos = (float)pos_ids[s];
        float inv_freq = expf(-(float)j * (9.210340371976184f / 32.f));
        float ang = pos * inv_freq;
        float c = cosf(ang), sn = sinf(ang);
        int i1 = Q_LORA + KV_LORA + j;
        int i2 = i1 + 32;
        float x1 = (r0[i1] + r0[i1 + PL]) + (r0[i1 + 2 * PL] + r0[i1 + 3 * PL]);
        float x2 = (r0[i2] + r0[i2 + PL]) + (r0[i2 + 2 * PL] + r0[i2 + 3 * PL]);
        row[i1] = (ushort_t)f2bf(x1 * c - x2 * sn);
        row[i2] = (ushort_t)f2bf(x2 * c + x1 * sn);
    }
}

// ---------------------------------------------------------------------------
// MFMA bf16 flash attention (causal) — round-10 proven structure (127.5us):
// counted-vmcnt 3-buffer SINGLE-barrier pipeline, load-balanced pair
// {31-p, p} processed as two sequential passes. NEW (extracted from round
// 11, correctness-proven there): RoPE on q_pe fused into the Q-load —
// pair (j, j+32) = elements e of qf[4]/qf[5] in the SAME lane; prologue-
// only temporaries so VGPR stays in the <=128 occupancy bucket.
// ---------------------------------------------------------------------------
__global__ __launch_bounds__(256) void attn_mfma(
    const ushort_t* __restrict__ q,
    const ushort_t* __restrict__ kv,
    const ushort_t* __restrict__ abuf,
    const ushort_t* __restrict__ vt,
    const int* __restrict__ pos_ids,
    ushort_t* __restrict__ attn)
{
    __shared__ short8 KF[3][768];   // 36 KB
    __shared__ short8 VF[3][512];   // 24 KB
    __shared__ short8 PA[256];      //  4 KB

    const int tid  = threadIdx.x;
    const int wave = tid >> 6;
    const int lane = tid & 63;
    const int m    = lane & 15;
    const int quad = lane >> 4;
    const int h    = blockIdx.y;
    const int pair = blockIdx.x;                  // 0..15
    const int qtiles[2] = { 31 - pair, pair };    // big tile first

    // exp2-domain scale: (1/sqrt(192)) * log2(e)
    const float scale2 = 0.07216878364870323f * 1.4426950408889634f;
    short* pas = (short*)PA;

    auto stage_kv = [&](int t0, int buf) {       // exactly 5 GLOAD16 / thread
        #pragma unroll
        for (int rep = 0; rep < 3; ++rep) {
            int i   = rep * 256 + tid;
            int key = i & 31, qd = (i >> 5) & 3, c = i >> 7;   // c wave-uniform
            if (c < 4)
                GLOAD16(kv + ((size_t)(t0 + key) * NHEAD + h) * 256 + c * 32 + qd * 8,
                        &KF[buf][i]);
            else
                GLOAD16(abuf + (size_t)(t0 + key) * FUSED_N + 2048 + (c - 4) * 32 + qd * 8,
                        &KF[buf][i]);
        }
        const ushort_t* vsrc = vt + ((size_t)h * (S_LEN / 8) + (t0 >> 3)) * 1024;
        GLOAD16(vsrc + (size_t)tid * 8, &VF[buf][tid]);
        GLOAD16(vsrc + (size_t)(256 + tid) * 8, &VF[buf][256 + tid]);
    };

    for (int qi = 0; qi < 2; ++qi) {
        const int q0 = qtiles[qi] * 64;
        const int qrow_base = q0 + wave * 16;

        // Q load + fused RoPE (pairs (j, j+32) live in qf[4][e] / qf[5][e],
        // j = quad*8 + e — same lane holds both halves of each pair)
        short8 qf[6];
        {
            const int rowQ = qrow_base + m;
            const ushort_t* qrow = q + ((size_t)rowQ * NHEAD + h) * QK_DIM;
            #pragma unroll
            for (int c = 0; c < 6; ++c)
                qf[c] = *(const short8*)(qrow + c * 32 + quad * 8);
            float pos = (float)pos_ids[rowQ];
            #pragma unroll
            for (int e = 0; e < 8; ++e) {
                int j = quad * 8 + e;
                float inv_freq = expf(-(float)j * (9.210340371976184f / 32.f));
                float ang = pos * inv_freq;
                float cc = cosf(ang), sn = sinf(ang);
                float x1 = bf2f((ushort_t)qf[4][e]), x2 = bf2f((ushort_t)qf[5][e]);
                qf[4][e] = f2bf(x1 * cc - x2 * sn);
                qf[5][e] = f2bf(x2 * cc + x1 * sn);
            }
        }

        floatx4 O[8];
        #pragma unroll
        for (int t = 0; t < 8; ++t) O[t] = (floatx4){0.f, 0.f, 0.f, 0.f};
        float mrow[4] = {-1e30f, -1e30f, -1e30f, -1e30f};
        float lrow[4] = {0.f, 0.f, 0.f, 0.f};

        const int ntile = (q0 + 64) / 32;        // always >= 2 (even)

        stage_kv(0, 0);                          // prologue: 1 tile ahead

        for (int tt = 0; tt < ntile; ++tt) {
            const int t0 = tt * 32;
            if (tt + 1 < ntile) {
                stage_kv(t0 + 32, (tt + 1) % 3);
                // 10 outstanding -> wait oldest 5 (= tile tt), 5 stay in flight
                asm volatile("s_waitcnt vmcnt(5)" ::: "memory");
            } else {
                asm volatile("s_waitcnt vmcnt(0)" ::: "memory");   // last tile done
            }
            asm volatile("s_barrier" ::: "memory");   // buf tt ready for ALL waves
            const int cur = tt % 3;

            floatx4 s0 = (floatx4){0.f, 0.f, 0.f, 0.f};
            floatx4 s1 = (floatx4){0.f, 0.f, 0.f, 0.f};
            const int kb = quad * 32 + m;
            __builtin_amdgcn_s_setprio(1);
            #pragma unroll
            for (int c = 0; c < 6; ++c) {
                s0 = __builtin_amdgcn_mfma_f32_16x16x32_bf16(qf[c], KF[cur][c * 128 + kb],      s0, 0, 0, 0);
                s1 = __builtin_amdgcn_mfma_f32_16x16x32_bf16(qf[c], KF[cur][c * 128 + kb + 16], s1, 0, 0, 0);
            }
            __builtin_amdgcn_s_setprio(0);

            const int qb = qrow_base + quad * 4;
            float sv0[4], sv1[4];
            #pragma unroll
            for (int r = 0; r < 4; ++r) {
                float a0 = s0[r] * scale2;       // exp2 domain
                float a1 = s1[r] * scale2;
                if (t0 + m > qb + r)      a0 = -1e30f;
                if (t0 + 16 + m > qb + r) a1 = -1e30f;
                sv0[r] = a0; sv1[r] = a1;
            }
            #pragma unroll
            for (int r = 0; r < 4; ++r) {
                float v = fmaxf(sv0[r], sv1[r]);            // per-lane max (2 keys)
                // fast path: no lane exceeds mrow+8 -> skip reduce + rescale
                if (!__all(v <= mrow[r] + 8.f)) {
                    v = fmaxf(v, __shfl_xor(v, 1));
                    v = fmaxf(v, __shfl_xor(v, 2));
                    v = fmaxf(v, __shfl_xor(v, 4));
                    v = fmaxf(v, __shfl_xor(v, 8));         // true row max
                    float mnew  = fmaxf(mrow[r], v);
                    float alpha = exp2f(mrow[r] - mnew);    // first tile: 2^-inf = 0
                    lrow[r] *= alpha;
                    #pragma unroll
                    for (int t = 0; t < 8; ++t) O[t][r] *= alpha;
                    mrow[r] = mnew;
                }
                float p0 = exp2f(sv0[r] - mrow[r]);         // bounded by 2^8
                float p1 = exp2f(sv1[r] - mrow[r]);
                lrow[r] += p0 + p1;                         // per-lane partial
                int row = quad * 4 + r;
                short* pw = pas + wave * 512;
                pw[((m >> 3) + 0) * 128 + row * 8 + (m & 7)] = f2bf(p0);
                pw[((m >> 3) + 2) * 128 + row * 8 + (m & 7)] = f2bf(p1);
            }

            short8 pfrag = PA[wave * 64 + quad * 16 + m];
            __builtin_amdgcn_s_setprio(1);
            #pragma unroll
            for (int t = 0; t < 8; ++t) {
                O[t] = __builtin_amdgcn_mfma_f32_16x16x32_bf16(
                    pfrag, VF[cur][quad * 128 + m + 16 * t], O[t], 0, 0, 0);
            }
            __builtin_amdgcn_s_setprio(0);
            // no trailing barrier (single-barrier scheme)
        }

        #pragma unroll
        for (int r = 0; r < 4; ++r) {
            float l = lrow[r];                           // reduce once at the end
            l += __shfl_xor(l, 1);
            l += __shfl_xor(l, 2);
            l += __shfl_xor(l, 4);
            l += __shfl_xor(l, 8);
            float linv = 1.f / l;
            int row = qrow_base + quad * 4 + r;
            ushort_t* dst = attn + ((size_t)row * NHEAD + h) * VDIM + m;
            #pragma unroll
            for (int t = 0; t < 8; ++t)
                dst[16 * t] = (ushort_t)f2bf(O[t][r] * linv);
        }
        // protect LDS slot reuse across q-tiles: next qi's prologue stages
        // slot 0 only after ALL waves finished this qi's last compute.
        asm volatile("s_barrier" ::: "memory");
    }
}

// ---------------------------------------------------------------------------
extern "C" void kernel_launch(void* const* d_in, const int* in_sizes, int n_in,
                              void* d_out, int out_size, void* d_ws, size_t ws_size,
                              hipStream_t stream)
{
    const int*   pos    = (const int*)d_in[0];
    const float* hs     = (const float*)d_in[1];
    const float* w_a    = (const float*)d_in[2];
    const float* qlnw   = (const float*)d_in[3];
    const float* kvlnw  = (const float*)d_in[4];
    const float* w_qb   = (const float*)d_in[5];
    const float* w_kvb  = (const float*)d_in[6];
    const float* w_o    = (const float*)d_in[7];
    float* out = (float*)d_out;

    // workspace layout — 163.8 MB total (>=168 MB known available)
    char* p = (char*)d_ws;
    ushort_t* a_bf    = (ushort_t*)p; p += (size_t)S_LEN * FUSED_N * 2;          //  8.65 MB
    ushort_t* q_bf    = (ushort_t*)p; p += (size_t)S_LEN * NHEAD * QK_DIM * 2;   // 25.2 MB
    ushort_t* kv_bf   = (ushort_t*)p; p += (size_t)S_LEN * NHEAD * 256 * 2;      // 33.6 MB
    ushort_t* attn_bf = (ushort_t*)p; p += (size_t)S_LEN * HID * 2;              // 16.8 MB
    ushort_t* hs_bf   = (ushort_t*)p; p += (size_t)S_LEN * HID * 2;              // 16.8 MB
    ushort_t* w_a_bf  = (ushort_t*)p; p += (size_t)FUSED_NPAD * HID * 2;         // 18.9 MB
    ushort_t* w_qb_bf = (ushort_t*)p; p += (size_t)NHEAD * QK_DIM * Q_LORA * 2;  // 18.9 MB
    ushort_t* w_kvb_bf= (ushort_t*)p; p += (size_t)NHEAD * 256 * KV_LORA * 2;    //  8.4 MB
    ushort_t* vt_bf   = (ushort_t*)p; p += (size_t)S_LEN * HID * 2;              // 16.8 MB
    // w_o_bf (33.6 MB) aliases hs_bf + w_a_bf, both dead after gemm 1
    ushort_t* w_o_bf  = hs_bf;
    // gemm1 split-K=4 fp32 partials (69.2 MB) in q_bf+kv_bf+attn_bf (75.5 MB)
    float* part1 = (float*)q_bf;
    // gemm7 split-K=2 fp32 partials (67.1 MB) in a_bf+q_bf+kv_bf (67.4 MB)
    float* part7 = (float*)a_bf;

    if (ws_size < (size_t)(p - (char*)d_ws)) return;  // fail loud, not fault

    dim3 blk(256);
    dim3 blk512(512);
    auto cgrid = [](size_t n) { return dim3((unsigned)((n / 8 + 255) / 256)); };

    // 0. merged fp32 -> bf16 (hs, w_a pad, w_qb, w_kvb) — one dispatch
    conv_all<<<dim3(CE3 / 2048), blk, 0, stream>>>(
        hs, w_a, w_qb, w_kvb, hs_bf, w_a_bf, w_qb_bf, w_kvb_bf);

    // 1. a = hs @ w_fused_a^T : pipelined 256^2, split-K=4 (288 blocks)
    gemm256p<float><<<dim3((FUSED_NPAD / 256) * (S_LEN / 256) * 4), blk512, 0, stream>>>(
        hs_bf, HID, w_a_bf, HID, part1, FUSED_N, FUSED_N, HID / 4,
        FUSED_NPAD / 256, S_LEN / 256);

    // 1b. w_o -> bf16 (into region freed by gemm 1)
    conv_bf16<<<cgrid((size_t)HID * HID), blk, 0, stream>>>(w_o, w_o_bf, HID * HID);

    // 2. fused split-K reduce (4 planes) + RMSNorm cq/ckv + k_pe RoPE -> a_bf
    norm_rope_kernel<<<S_LEN, 256, 0, stream>>>(part1, a_bf, qlnw, kvlnw, pos);

    // 3+4. merged q/kv projection GEMMs, pipelined, V-transpose fused (448 blocks)
    gemm34p<<<dim3(56 * (S_LEN / 256)), blk512, 0, stream>>>(
        a_bf, w_qb_bf, w_kvb_bf, q_bf, kv_bf, vt_bf);

    // 5+6. MFMA flash attention (q_pe RoPE fused into Q-load) -> attn
    attn_mfma<<<dim3(16, NHEAD), blk, 0, stream>>>(
        q_bf, kv_bf, a_bf, vt_bf, pos, attn_bf);

    // 7. out = attn @ w_o^T : pipelined 256^2, split-K=2 (256 blocks), then add
    gemm256p<float><<<dim3((HID / 256) * (S_LEN / 256) * 2), blk512, 0, stream>>>(
        attn_bf, HID, w_o_bf, HID, part7, HID, HID, HID / 2,
        HID / 256, S_LEN / 256);
    reduce_add_f32<<<cgrid((size_t)S_LEN * HID * 2), blk, 0, stream>>>(
        part7, part7 + (size_t)S_LEN * HID, out, S_LEN * HID);
}